// Round 6
// baseline (226.693 us; speedup 1.0000x reference)
//
#include <hip/hip_runtime.h>
#include <stdint.h>

// ---------------------------------------------------------------------------
// MultiScaleGRU fused pipeline (MI355X / gfx950)
//
//   gi = (A @ C) @ w_ih^T + b_ih      A: [16384,4096] fp32 (attention_weights)
//   gh = h @ w_hh^T + b_hh            h: repeat(C[:16], 4)  -> [64,256]
//   r,z = sigmoid(gi_rz + gh_rz); n = tanh(gi_n + r*gh_n)
//   h_new = (1-z)*n + z*h ; out[o,b,:] = mean_j h_new[b, 4o+j, :]
//
// Precision plan (threshold 7.5e-2, last run 1.02e-1 = pure bf16 noise):
//  - A centered: stage bf16(a-0.5)  -> halves A-quant ulp; exact fp32
//    correction 0.5*colsum(C)[h] added in stage-1 epilogue.
//  - C split hi+lo bf16: X = A'@C_hi + A'@C_lo (same accumulator).
//  - X carried as hi+lo bf16 split (exact to 2^-18 rel).
//  - W split hi+lo bf16: GI = Xhi@Whi + Xlo@Whi + Xhi@Wlo.
//  Residual gi error sigma ~0.012 -> predicted absmax ~0.03.
//
// All bf16 tiles stored pre-XOR-swizzled (16B chunk j ^= row&7 within each
// 128B segment) so global_load_lds (linear dest) + swizzled ds_read_b128 is
// bank-conflict-free (guide G4 / T2 / rule 21).
// ---------------------------------------------------------------------------

typedef short short8 __attribute__((ext_vector_type(8)));
typedef float f32x4 __attribute__((ext_vector_type(4)));

// workspace layout (bytes)
#define WS_CTH  0u          // Ct hi : bf16 [256][4096] swz   (2 MB)
#define WS_CTL  2097152u    // Ct lo : bf16 [256][4096] swz   (2 MB)
#define WS_WPH  4194304u    // Wp hi : bf16 [768][256]  swz   (384 KB)
#define WS_WPL  4587520u    // Wp lo : bf16 [768][256]  swz   (384 KB)
#define WS_GH   4980736u    // GH    : f32  [64][768]         (192 KB)
#define WS_CSP  5177344u    // csum partials: f32 [16][256]   (16 KB)
#define WS_CS   5193728u    // csum  : f32 [256]              (1 KB)
#define WS_XHI  5194752u    // Xhi   : bf16 [16384][256] swz  (8 MB)
#define WS_XLO  13583360u   // Xlo   : bf16 [16384][256] swz  (8 MB)
// total 21,971,968 bytes

static __device__ __forceinline__ unsigned short f2bf(float x) {
  // fp32 -> bf16 round-to-nearest-even (explicit; avoids truncation bias)
  unsigned u = __builtin_bit_cast(unsigned, x);
  u += 0x7FFFu + ((u >> 16) & 1u);
  return (unsigned short)(u >> 16);
}
static __device__ __forceinline__ float bf2f(unsigned short h) {
  unsigned u = ((unsigned)h) << 16;
  return __builtin_bit_cast(float, u);
}
static __device__ __forceinline__ void gload16(const void* g, void* lds) {
  // async global->LDS, 16B per lane; LDS dest = wave-uniform base + lane*16
  __builtin_amdgcn_global_load_lds(
      (const __attribute__((address_space(1))) unsigned int*)g,
      (__attribute__((address_space(3))) unsigned int*)lds, 16, 0, 0);
}
static __device__ __forceinline__ float sigmf(float x) {
  float e = __expf(-fabsf(x));
  float p = 1.f / (1.f + e);
  return x >= 0.f ? p : 1.f - p;
}
static __device__ __forceinline__ float tanhf2(float x) {
  float e = __expf(-2.f * fabsf(x));
  float t = 1.f - 2.f * e / (1.f + e);
  return x >= 0.f ? t : -t;
}

// ---------------------------------------------------------------------------
// prep 1: C[4096][256] f32 -> Ct_hi/Ct_lo [256(h)][4096(f)] bf16, swizzled
__global__ void __launch_bounds__(256) k_transC(const float* __restrict__ C,
                                                unsigned short* __restrict__ Cth,
                                                unsigned short* __restrict__ Ctl) {
  __shared__ float sT[64][65];
  const int f0 = blockIdx.x * 64, h0 = blockIdx.y * 64;
  const int t = threadIdx.x;
#pragma unroll
  for (int i = 0; i < 4; ++i) {
    int fl = t + 256 * i;
    int r = fl >> 4, c4 = fl & 15;
    float4 v = *(const float4*)(C + (size_t)(f0 + r) * 256 + h0 + c4 * 4);
    sT[r][c4 * 4 + 0] = v.x; sT[r][c4 * 4 + 1] = v.y;
    sT[r][c4 * 4 + 2] = v.z; sT[r][c4 * 4 + 3] = v.w;
  }
  __syncthreads();
#pragma unroll
  for (int i = 0; i < 2; ++i) {
    int q = t + 256 * i;         // 512 chunks of 8 bf16
    int hr = q >> 3, j = q & 7;  // out row (h), f-chunk within 64
    int h = h0 + hr;
    union { short8 v; unsigned short u[8]; } ph, pl;
#pragma unroll
    for (int u = 0; u < 8; ++u) {
      float v = sT[j * 8 + u][hr];
      unsigned short hi = f2bf(v);
      ph.u[u] = hi;
      pl.u[u] = f2bf(v - bf2f(hi));
    }
    size_t off = (size_t)h * 8192 + (size_t)f0 * 2 + (size_t)((j ^ (h & 7)) << 4);
    *(short8*)((char*)Cth + off) = ph.v;
    *(short8*)((char*)Ctl + off) = pl.v;
  }
}

// prep 1b: colsum partials (deterministic 2-step tree, no fp32 atomics)
__global__ void __launch_bounds__(256) k_csum(const float* __restrict__ C,
                                              float* __restrict__ part) {
  const int b = blockIdx.x, t = threadIdx.x;
  float s = 0.f;
  for (int k = 0; k < 256; ++k) s += C[(size_t)(b * 256 + k) * 256 + t];
  part[b * 256 + t] = s;
}
__global__ void __launch_bounds__(256) k_csum2(const float* __restrict__ part,
                                               float* __restrict__ csum) {
  const int t = threadIdx.x;
  float s = 0.f;
#pragma unroll
  for (int b = 0; b < 16; ++b) s += part[b * 256 + t];
  csum[t] = 0.5f * s;  // correction for A centered at 0.5
}

// prep 2: w_ih[768][256] f32 -> Wp_hi/Wp_lo [n'=3h+g][256] bf16, swizzled
__global__ void __launch_bounds__(256) k_prepWp(const float* __restrict__ w_ih,
                                                unsigned short* __restrict__ Wph,
                                                unsigned short* __restrict__ Wpl) {
  int q = blockIdx.x * 256 + threadIdx.x;  // 24576 chunks
  int row = q >> 5, c = q & 31;
  int seg = c >> 3, j = c & 7;
  int srow = (row % 3) * 256 + row / 3;    // gate-interleave permutation
  const float* src = w_ih + (size_t)srow * 256 + c * 8;
  union { short8 v; unsigned short u[8]; } ph, pl;
#pragma unroll
  for (int u = 0; u < 8; ++u) {
    float v = src[u];
    unsigned short hi = f2bf(v);
    ph.u[u] = hi;
    pl.u[u] = f2bf(v - bf2f(hi));
  }
  size_t off = (size_t)row * 512 + seg * 128 + ((j ^ (row & 7)) << 4);
  *(short8*)((char*)Wph + off) = ph.v;
  *(short8*)((char*)Wpl + off) = pl.v;
}

// prep 3: GH[64][768] = h @ w_hh^T + b_hh   (exact fp32)
__global__ void __launch_bounds__(256) k_gh(const float* __restrict__ centers,
                                            const float* __restrict__ w_hh,
                                            const float* __restrict__ b_hh,
                                            float* __restrict__ GH) {
  __shared__ __align__(16) float sH[256];
  const int s = blockIdx.x, t = threadIdx.x;
  sH[t] = centers[(size_t)(s >> 2) * 256 + t];
  __syncthreads();
#pragma unroll
  for (int e = 0; e < 3; ++e) {
    int n = e * 256 + t;
    float accv = b_hh[n];
    const float4* w = (const float4*)(w_hh + (size_t)n * 256);
#pragma unroll 8
    for (int k = 0; k < 64; ++k) {
      float4 v = w[k];
      float4 hh = *(const float4*)&sH[k * 4];
      accv += v.x * hh.x + v.y * hh.y + v.z * hh.z + v.w * hh.w;
    }
    GH[(size_t)s * 768 + n] = accv;
  }
}

// ---------------------------------------------------------------------------
// stage 1: X = (A-0.5) @ (C_hi + C_lo) + 0.5*colsum(C).
// BM=32, BN=256(full H), BK=64. grid 512, 256 thr.
// A fp32 reg-staged, centered, RNE cvt -> swizzled LDS; B via global_load_lds.
// Epilogue: X -> hi/lo bf16 split, stored pre-swizzled.
__global__ void __launch_bounds__(256) k_stage1(const float* __restrict__ A,
                                                const unsigned short* __restrict__ Cth,
                                                const unsigned short* __restrict__ Ctl,
                                                const float* __restrict__ csum,
                                                unsigned short* __restrict__ Xhi,
                                                unsigned short* __restrict__ Xlo) {
  __shared__ __align__(16) short sA[32 * 64];    //  4 KB
  __shared__ __align__(16) short sBh[256 * 64];  // 32 KB
  __shared__ __align__(16) short sBl[256 * 64];  // 32 KB
  const int t = threadIdx.x;
  const int wid = t >> 6, l = t & 63;
  const int lr = l & 15, lk = l >> 4;
  const int m0 = blockIdx.x * 32;

  f32x4 acc[2][4];
#pragma unroll
  for (int i = 0; i < 2; ++i)
#pragma unroll
    for (int j = 0; j < 4; ++j) acc[i][j] = (f32x4){0.f, 0.f, 0.f, 0.f};

  const int ar = t >> 3, aj = t & 7;  // A staging: row 0..31, 8-float chunk 0..7
  const float* aptr = A + (size_t)(m0 + ar) * 4096 + aj * 8;
  const int saw = ar * 128 + ((aj ^ (ar & 7)) << 4);

  float4 a0 = *(const float4*)aptr;
  float4 a1 = *(const float4*)(aptr + 4);

  for (int kk = 0; kk < 64; ++kk) {
    __syncthreads();
    // B tiles: 256 rows x 64 bf16 each via global_load_lds (source pre-swz)
#pragma unroll
    for (int i = 0; i < 8; ++i) {
      int flat = t + 256 * i;
      int r = flat >> 3, j = flat & 7;
      gload16(Cth + (size_t)r * 4096 + kk * 64 + j * 8,
              (char*)sBh + (wid * 64 + 256 * i) * 16);
      gload16(Ctl + (size_t)r * 4096 + kk * 64 + j * 8,
              (char*)sBl + (wid * 64 + 256 * i) * 16);
    }
    // A tile: center, cvt prefetched regs -> swizzled ds_write_b128
    {
      union { short8 v; unsigned short u[8]; } pk;
      pk.u[0] = f2bf(a0.x - 0.5f); pk.u[1] = f2bf(a0.y - 0.5f);
      pk.u[2] = f2bf(a0.z - 0.5f); pk.u[3] = f2bf(a0.w - 0.5f);
      pk.u[4] = f2bf(a1.x - 0.5f); pk.u[5] = f2bf(a1.y - 0.5f);
      pk.u[6] = f2bf(a1.z - 0.5f); pk.u[7] = f2bf(a1.w - 0.5f);
      *(short8*)((char*)sA + saw) = pk.v;
    }
    if (kk < 63) {  // prefetch next A chunk (issued early)
      a0 = *(const float4*)(aptr + (kk + 1) * 64);
      a1 = *(const float4*)(aptr + (kk + 1) * 64 + 4);
    }
    __syncthreads();
#pragma unroll
    for (int kc = 0; kc < 2; ++kc) {
      short8 af[2], bh[4], bl[4];
      const int q = kc * 4 + lk;
#pragma unroll
      for (int mi = 0; mi < 2; ++mi) {
        int r = mi * 16 + lr;
        af[mi] = *(const short8*)((const char*)sA + r * 128 + ((q ^ (r & 7)) << 4));
      }
#pragma unroll
      for (int ni = 0; ni < 4; ++ni) {
        int r = wid * 64 + ni * 16 + lr;
        int so = r * 128 + ((q ^ (r & 7)) << 4);
        bh[ni] = *(const short8*)((const char*)sBh + so);
        bl[ni] = *(const short8*)((const char*)sBl + so);
      }
#pragma unroll
      for (int mi = 0; mi < 2; ++mi)
#pragma unroll
        for (int ni = 0; ni < 4; ++ni) {
          acc[mi][ni] = __builtin_amdgcn_mfma_f32_16x16x32_bf16(af[mi], bh[ni], acc[mi][ni], 0, 0, 0);
          acc[mi][ni] = __builtin_amdgcn_mfma_f32_16x16x32_bf16(af[mi], bl[ni], acc[mi][ni], 0, 0, 0);
        }
    }
  }

  // epilogue: add centering correction, X -> hi/lo bf16, pre-swizzled storage
  float cs[4];
#pragma unroll
  for (int ni = 0; ni < 4; ++ni) cs[ni] = csum[wid * 64 + ni * 16 + lr];
#pragma unroll
  for (int mi = 0; mi < 2; ++mi)
#pragma unroll
    for (int ni = 0; ni < 4; ++ni)
#pragma unroll
      for (int p = 0; p < 4; ++p) {
        int m = m0 + mi * 16 + lk * 4 + p;        // C/D: row=(lane>>4)*4+reg
        int col = wid * 64 + ni * 16 + lr;        //      col=lane&15
        float x = acc[mi][ni][p] + cs[ni];
        unsigned short hi = f2bf(x);
        unsigned short lo = f2bf(x - bf2f(hi));
        size_t off = (size_t)m * 512 + ((col >> 6) << 7) +
                     ((((col >> 3) & 7) ^ (m & 7)) << 4) + ((col & 7) << 1);
        *(unsigned short*)((char*)Xhi + off) = hi;
        *(unsigned short*)((char*)Xlo + off) = lo;
      }
}

// ---------------------------------------------------------------------------
// stage 2: GI = Xhi@Whi + Xlo@Whi + Xhi@Wlo (virtual K=768) + fused GRU.
// BM=128, BN=96 (32 h * 3 gates), grid (8,128), 256 thr (4 waves 2Mx2N).
__global__ void __launch_bounds__(256) k_stage2(const unsigned short* __restrict__ Xhi,
                                                const unsigned short* __restrict__ Xlo,
                                                const unsigned short* __restrict__ Wph,
                                                const unsigned short* __restrict__ Wpl,
                                                const float* __restrict__ GH,
                                                const float* __restrict__ centers,
                                                const float* __restrict__ b_ih,
                                                float* __restrict__ out) {
  __shared__ __align__(16) char smem[51200];
  short* sA = (short*)smem;            // [128][64] bf16 swz : 16 KB
  short* sB = (short*)(smem + 16384);  // [96][64]  bf16 swz : 12 KB
  float* sC = (float*)smem;            // [128][100] f32 (epilogue reuse)
  const int t = threadIdx.x;
  const int wid = t >> 6, l = t & 63;
  const int lr = l & 15, lk = l >> 4;
  const int wm = wid >> 1, wn = wid & 1;
  const int n0 = blockIdx.x * 96;
  const int m0 = blockIdx.y * 128;

  f32x4 acc[4][3];
#pragma unroll
  for (int i = 0; i < 4; ++i)
#pragma unroll
    for (int j = 0; j < 3; ++j) acc[i][j] = (f32x4){0.f, 0.f, 0.f, 0.f};

#pragma unroll
  for (int pass = 0; pass < 3; ++pass) {
    const unsigned short* Xs = (pass == 1) ? Xlo : Xhi;
    const unsigned short* Ws = (pass == 2) ? Wpl : Wph;
    for (int seg = 0; seg < 4; ++seg) {
      __syncthreads();
#pragma unroll
      for (int i = 0; i < 4; ++i) {  // A: 128x64 bf16
        int flat = t + 256 * i;
        int r = flat >> 3, j = flat & 7;
        gload16((const char*)Xs + (size_t)(m0 + r) * 512 + seg * 128 + j * 16,
                (char*)sA + (wid * 64 + 256 * i) * 16);
      }
#pragma unroll
      for (int i = 0; i < 3; ++i) {  // B: 96x64 bf16
        int flat = t + 256 * i;
        int r = flat >> 3, j = flat & 7;
        gload16((const char*)Ws + (size_t)(n0 + r) * 512 + seg * 128 + j * 16,
                (char*)sB + (wid * 64 + 256 * i) * 16);
      }
      __syncthreads();
#pragma unroll
      for (int kc = 0; kc < 2; ++kc) {
        short8 af[4], bfv[3];
        const int q = kc * 4 + lk;
#pragma unroll
        for (int mi = 0; mi < 4; ++mi) {
          int r = wm * 64 + mi * 16 + lr;
          af[mi] = *(const short8*)((const char*)sA + r * 128 + ((q ^ (r & 7)) << 4));
        }
#pragma unroll
        for (int ni = 0; ni < 3; ++ni) {
          int r = wn * 48 + ni * 16 + lr;
          bfv[ni] = *(const short8*)((const char*)sB + r * 128 + ((q ^ (r & 7)) << 4));
        }
#pragma unroll
        for (int mi = 0; mi < 4; ++mi)
#pragma unroll
          for (int ni = 0; ni < 3; ++ni)
            acc[mi][ni] = __builtin_amdgcn_mfma_f32_16x16x32_bf16(af[mi], bfv[ni], acc[mi][ni], 0, 0, 0);
      }
    }
  }
  __syncthreads();  // all LDS reads done before sC overwrites sA/sB
#pragma unroll
  for (int mi = 0; mi < 4; ++mi)
#pragma unroll
    for (int ni = 0; ni < 3; ++ni)
#pragma unroll
      for (int p = 0; p < 4; ++p) {
        int row = wm * 64 + mi * 16 + lk * 4 + p;
        int colc = wn * 48 + ni * 16 + lr;
        sC[row * 100 + colc] = acc[mi][ni][p];
      }
  __syncthreads();
  // fused GRU + level-mean: 32 groups x 32 h per block, 4 (g,h) pairs/thread
#pragma unroll
  for (int i = 0; i < 4; ++i) {
    int p = t + 256 * i;
    int g = p >> 5, hl = p & 31;
    int h_idx = blockIdx.x * 32 + hl;
    int o = g & 15;
    int bidx = (m0 >> 6) + (g >> 4);
    float hprev = centers[o * 256 + h_idx];
    float bir = b_ih[h_idx], biz = b_ih[256 + h_idx], bin = b_ih[512 + h_idx];
    float sum = 0.f;
#pragma unroll
    for (int j = 0; j < 4; ++j) {
      int rl = 4 * g + j;   // local row in sC
      int ss = 4 * o + j;   // slot s
      float gir = sC[rl * 100 + 3 * hl + 0] + bir;
      float giz = sC[rl * 100 + 3 * hl + 1] + biz;
      float gin = sC[rl * 100 + 3 * hl + 2] + bin;
      float rg = sigmf(gir + GH[ss * 768 + h_idx]);
      float zg = sigmf(giz + GH[ss * 768 + 256 + h_idx]);
      float ng = tanhf2(gin + rg * GH[ss * 768 + 512 + h_idx]);
      sum += (1.f - zg) * ng + zg * hprev;
    }
    out[(size_t)o * 65536 + (size_t)bidx * 256 + h_idx] = 0.25f * sum;
  }
}

// ---------------------------------------------------------------------------
extern "C" void kernel_launch(void* const* d_in, const int* in_sizes, int n_in,
                              void* d_out, int out_size, void* d_ws, size_t ws_size,
                              hipStream_t stream) {
  (void)in_sizes; (void)n_in; (void)out_size; (void)ws_size;
  const float* attn    = (const float*)d_in[0];  // [256][64][4096]
  const float* centers = (const float*)d_in[1];  // [4096][256]
  const float* w_ih    = (const float*)d_in[2];  // [768][256]
  const float* w_hh    = (const float*)d_in[3];  // [768][256]
  const float* b_ih    = (const float*)d_in[4];  // [768]
  const float* b_hh    = (const float*)d_in[5];  // [768]

  char* ws = (char*)d_ws;
  unsigned short* Cth = (unsigned short*)(ws + WS_CTH);
  unsigned short* Ctl = (unsigned short*)(ws + WS_CTL);
  unsigned short* Wph = (unsigned short*)(ws + WS_WPH);
  unsigned short* Wpl = (unsigned short*)(ws + WS_WPL);
  float*          GHp = (float*)(ws + WS_GH);
  float*          csp = (float*)(ws + WS_CSP);
  float*          cs  = (float*)(ws + WS_CS);
  unsigned short* Xhi = (unsigned short*)(ws + WS_XHI);
  unsigned short* Xlo = (unsigned short*)(ws + WS_XLO);
  float* out = (float*)d_out;

  hipLaunchKernelGGL(k_transC, dim3(64, 4), dim3(256), 0, stream, centers, Cth, Ctl);
  hipLaunchKernelGGL(k_csum, dim3(16), dim3(256), 0, stream, centers, csp);
  hipLaunchKernelGGL(k_csum2, dim3(1), dim3(256), 0, stream, csp, cs);
  hipLaunchKernelGGL(k_prepWp, dim3(96), dim3(256), 0, stream, w_ih, Wph, Wpl);
  hipLaunchKernelGGL(k_gh, dim3(64), dim3(256), 0, stream, centers, w_hh, b_hh, GHp);
  hipLaunchKernelGGL(k_stage1, dim3(512), dim3(256), 0, stream, attn, Cth, Ctl, cs, Xhi, Xlo);
  hipLaunchKernelGGL(k_stage2, dim3(8, 128), dim3(256), 0, stream, Xhi, Xlo, Wph, Wpl, GHp, centers, b_ih, out);
}

// Round 7
// 217.595 us; speedup vs baseline: 1.0418x; 1.0418x over previous
//
#include <hip/hip_runtime.h>
#include <stdint.h>

// ---------------------------------------------------------------------------
// MultiScaleGRU fused pipeline (MI355X / gfx950)
//
//   gi = (A @ C) @ w_ih^T + b_ih      A: [16384,4096] fp32 (attention_weights)
//   gh = h @ w_hh^T + b_hh            h: repeat(C[:16], 4)  -> [64,256]
//   r,z = sigmoid(gi_rz + gh_rz); n = tanh(gi_n + r*gh_n)
//   h_new = (1-z)*n + z*h ; out[o,b,:] = mean_j h_new[b, 4o+j, :]
//
// Precision plan (passing: absmax 0.0195 vs 7.5e-2):
//  - A centered bf16(a-0.5) + exact 0.5*colsum(C) correction.
//  - C split hi+lo bf16; X carried hi+lo bf16; W split hi+lo bf16
//    (GI = Xh@Wh + Xl@Wh + Xh@Wl). Accumulation order preserved this round.
//
// Perf restructure (R6): stage1 was L3-BW-bound on Ct re-reads
// (512 blocks x 4MB = 2GB @ ~11 TB/s = 190us). Now BM=64, grid 256
// (1 block/CU, lockstep L2-resident B tiles) + 2-phase double-buffered
// B pipeline (raw s_barrier + lgkmcnt fence; single vmcnt(0) drain per
// tile via trailing __syncthreads). Stage2: X panel resident in LDS,
// W streamed once per block.
// ---------------------------------------------------------------------------

typedef short short8 __attribute__((ext_vector_type(8)));
typedef float f32x4 __attribute__((ext_vector_type(4)));

// workspace layout (bytes)
#define WS_CTH  0u          // Ct hi : bf16 [256][4096] swz   (2 MB)
#define WS_CTL  2097152u    // Ct lo : bf16 [256][4096] swz   (2 MB)
#define WS_WPH  4194304u    // Wp hi : bf16 [768][256]  swz   (384 KB)
#define WS_WPL  4587520u    // Wp lo : bf16 [768][256]  swz   (384 KB)
#define WS_GH   4980736u    // GH    : f32  [64][768]         (192 KB)
#define WS_CSP  5177344u    // csum partials: f32 [16][256]   (16 KB)
#define WS_CS   5193728u    // csum  : f32 [256]              (1 KB)
#define WS_XHI  5194752u    // Xhi   : bf16 [16384][256] swz  (8 MB)
#define WS_XLO  13583360u   // Xlo   : bf16 [16384][256] swz  (8 MB)
// total 21,971,968 bytes

static __device__ __forceinline__ unsigned short f2bf(float x) {
  // fp32 -> bf16 round-to-nearest-even (explicit; avoids truncation bias)
  unsigned u = __builtin_bit_cast(unsigned, x);
  u += 0x7FFFu + ((u >> 16) & 1u);
  return (unsigned short)(u >> 16);
}
static __device__ __forceinline__ float bf2f(unsigned short h) {
  unsigned u = ((unsigned)h) << 16;
  return __builtin_bit_cast(float, u);
}
static __device__ __forceinline__ void gload16(const void* g, void* lds) {
  // async global->LDS, 16B/lane; LDS dest = wave-uniform base + lane*16
  __builtin_amdgcn_global_load_lds(
      (const __attribute__((address_space(1))) unsigned int*)g,
      (__attribute__((address_space(3))) unsigned int*)lds, 16, 0, 0);
}
static __device__ __forceinline__ float sigmf(float x) {
  float e = __expf(-fabsf(x));
  float p = 1.f / (1.f + e);
  return x >= 0.f ? p : 1.f - p;
}
static __device__ __forceinline__ float tanhf2(float x) {
  float e = __expf(-2.f * fabsf(x));
  float t = 1.f - 2.f * e / (1.f + e);
  return x >= 0.f ? t : -t;
}

// ---------------------------------------------------------------------------
// prep 1: C[4096][256] f32 -> Ct_hi/Ct_lo [256(h)][4096(f)] bf16, swizzled
__global__ void __launch_bounds__(256) k_transC(const float* __restrict__ C,
                                                unsigned short* __restrict__ Cth,
                                                unsigned short* __restrict__ Ctl) {
  __shared__ float sT[64][65];
  const int f0 = blockIdx.x * 64, h0 = blockIdx.y * 64;
  const int t = threadIdx.x;
#pragma unroll
  for (int i = 0; i < 4; ++i) {
    int fl = t + 256 * i;
    int r = fl >> 4, c4 = fl & 15;
    float4 v = *(const float4*)(C + (size_t)(f0 + r) * 256 + h0 + c4 * 4);
    sT[r][c4 * 4 + 0] = v.x; sT[r][c4 * 4 + 1] = v.y;
    sT[r][c4 * 4 + 2] = v.z; sT[r][c4 * 4 + 3] = v.w;
  }
  __syncthreads();
#pragma unroll
  for (int i = 0; i < 2; ++i) {
    int q = t + 256 * i;         // 512 chunks of 8 bf16
    int hr = q >> 3, j = q & 7;  // out row (h), f-chunk within 64
    int h = h0 + hr;
    union { short8 v; unsigned short u[8]; } ph, pl;
#pragma unroll
    for (int u = 0; u < 8; ++u) {
      float v = sT[j * 8 + u][hr];
      unsigned short hi = f2bf(v);
      ph.u[u] = hi;
      pl.u[u] = f2bf(v - bf2f(hi));
    }
    size_t off = (size_t)h * 8192 + (size_t)f0 * 2 + (size_t)((j ^ (h & 7)) << 4);
    *(short8*)((char*)Cth + off) = ph.v;
    *(short8*)((char*)Ctl + off) = pl.v;
  }
}

// prep 1b: colsum partials (deterministic 2-step tree, no fp32 atomics)
__global__ void __launch_bounds__(256) k_csum(const float* __restrict__ C,
                                              float* __restrict__ part) {
  const int b = blockIdx.x, t = threadIdx.x;
  float s = 0.f;
  for (int k = 0; k < 256; ++k) s += C[(size_t)(b * 256 + k) * 256 + t];
  part[b * 256 + t] = s;
}
__global__ void __launch_bounds__(256) k_csum2(const float* __restrict__ part,
                                               float* __restrict__ csum) {
  const int t = threadIdx.x;
  float s = 0.f;
#pragma unroll
  for (int b = 0; b < 16; ++b) s += part[b * 256 + t];
  csum[t] = 0.5f * s;  // correction for A centered at 0.5
}

// prep 2: w_ih[768][256] f32 -> Wp_hi/Wp_lo [n'=3h+g][256] bf16, swizzled
__global__ void __launch_bounds__(256) k_prepWp(const float* __restrict__ w_ih,
                                                unsigned short* __restrict__ Wph,
                                                unsigned short* __restrict__ Wpl) {
  int q = blockIdx.x * 256 + threadIdx.x;  // 24576 chunks
  int row = q >> 5, c = q & 31;
  int seg = c >> 3, j = c & 7;
  int srow = (row % 3) * 256 + row / 3;    // gate-interleave permutation
  const float* src = w_ih + (size_t)srow * 256 + c * 8;
  union { short8 v; unsigned short u[8]; } ph, pl;
#pragma unroll
  for (int u = 0; u < 8; ++u) {
    float v = src[u];
    unsigned short hi = f2bf(v);
    ph.u[u] = hi;
    pl.u[u] = f2bf(v - bf2f(hi));
  }
  size_t off = (size_t)row * 512 + seg * 128 + ((j ^ (row & 7)) << 4);
  *(short8*)((char*)Wph + off) = ph.v;
  *(short8*)((char*)Wpl + off) = pl.v;
}

// prep 3: GH[64][768] = h @ w_hh^T + b_hh   (exact fp32)
__global__ void __launch_bounds__(256) k_gh(const float* __restrict__ centers,
                                            const float* __restrict__ w_hh,
                                            const float* __restrict__ b_hh,
                                            float* __restrict__ GH) {
  __shared__ __align__(16) float sH[256];
  const int s = blockIdx.x, t = threadIdx.x;
  sH[t] = centers[(size_t)(s >> 2) * 256 + t];
  __syncthreads();
#pragma unroll
  for (int e = 0; e < 3; ++e) {
    int n = e * 256 + t;
    float accv = b_hh[n];
    const float4* w = (const float4*)(w_hh + (size_t)n * 256);
#pragma unroll 8
    for (int k = 0; k < 64; ++k) {
      float4 v = w[k];
      float4 hh = *(const float4*)&sH[k * 4];
      accv += v.x * hh.x + v.y * hh.y + v.z * hh.z + v.w * hh.w;
    }
    GH[(size_t)s * 768 + n] = accv;
  }
}

// ---------------------------------------------------------------------------
// stage 1: X = (A-0.5) @ (C_hi + C_lo) + 0.5*colsum(C).
// BM=64, BN=256(full H), BK=64. grid 256 (1 block/CU), 256 thr, 4 waves 2Mx2N.
// 2-phase pipeline: B double-buffered via global_load_lds, next tile issued
// before the compute barrier (raw s_barrier + lgkmcnt fence); trailing
// __syncthreads() is the single vmcnt(0) drain per tile.
__global__ void __launch_bounds__(256) k_stage1(const float* __restrict__ A,
                                                const unsigned short* __restrict__ Cth,
                                                const unsigned short* __restrict__ Ctl,
                                                const float* __restrict__ csum,
                                                unsigned short* __restrict__ Xhi,
                                                unsigned short* __restrict__ Xlo) {
  __shared__ __align__(16) short sA[64 * 64];       //  8 KB
  __shared__ __align__(16) short sBh[2][256 * 64];  // 64 KB (dbuf)
  __shared__ __align__(16) short sBl[2][256 * 64];  // 64 KB (dbuf)
  const int t = threadIdx.x;
  const int wid = t >> 6, l = t & 63;
  const int lr = l & 15, lk = l >> 4;
  const int wm = wid >> 1, wn = wid & 1;
  const int m0 = blockIdx.x * 64;

  f32x4 acc[2][8];
#pragma unroll
  for (int i = 0; i < 2; ++i)
#pragma unroll
    for (int j = 0; j < 8; ++j) acc[i][j] = (f32x4){0.f, 0.f, 0.f, 0.f};

  // A staging: thread t -> row ar (0..63), 16-float chunk aq (0..3)
  const int ar = t >> 2, aq = t & 3;
  const float* aptr = A + (size_t)(m0 + ar) * 4096 + aq * 16;
  const int sw0 = ar * 128 + (((2 * aq) ^ (ar & 7)) << 4);
  const int sw1 = ar * 128 + (((2 * aq + 1) ^ (ar & 7)) << 4);

  // B staging: flat = t + 256*i -> row br+32i, chunk bj; dest = linear chunk
  const int br = t >> 3, bj = t & 7;

  // prologue: A(0) regs + B(0) -> buf 0
  float4 a0 = *(const float4*)(aptr);
  float4 a1 = *(const float4*)(aptr + 4);
  float4 a2 = *(const float4*)(aptr + 8);
  float4 a3 = *(const float4*)(aptr + 12);
#pragma unroll
  for (int i = 0; i < 8; ++i) {
    size_t so = (size_t)(br + 32 * i) * 4096 + bj * 8;
    int db = (wid * 64 + 256 * i) * 16;
    gload16(Cth + so, (char*)&sBh[0][0] + db);
    gload16(Ctl + so, (char*)&sBl[0][0] + db);
  }
  asm volatile("s_waitcnt vmcnt(0)" ::: "memory");

#pragma unroll 2
  for (int kk = 0; kk < 64; ++kk) {
    const int cur = kk & 1;
    // ds_write A(kk) (centered, RNE) -> sA  [prev reads fenced by last barrier]
    {
      union { short8 v; unsigned short u[8]; } p0, p1;
      p0.u[0] = f2bf(a0.x - 0.5f); p0.u[1] = f2bf(a0.y - 0.5f);
      p0.u[2] = f2bf(a0.z - 0.5f); p0.u[3] = f2bf(a0.w - 0.5f);
      p0.u[4] = f2bf(a1.x - 0.5f); p0.u[5] = f2bf(a1.y - 0.5f);
      p0.u[6] = f2bf(a1.z - 0.5f); p0.u[7] = f2bf(a1.w - 0.5f);
      p1.u[0] = f2bf(a2.x - 0.5f); p1.u[1] = f2bf(a2.y - 0.5f);
      p1.u[2] = f2bf(a2.z - 0.5f); p1.u[3] = f2bf(a2.w - 0.5f);
      p1.u[4] = f2bf(a3.x - 0.5f); p1.u[5] = f2bf(a3.y - 0.5f);
      p1.u[6] = f2bf(a3.z - 0.5f); p1.u[7] = f2bf(a3.w - 0.5f);
      *(short8*)((char*)sA + sw0) = p0.v;
      *(short8*)((char*)sA + sw1) = p1.v;
    }
    // issue next tile: A(kk+1) -> regs, B(kk+1) -> buf[cur^1]
    float4 n0, n1, n2, n3;
    if (kk < 63) {
      const float* ap = aptr + (kk + 1) * 64;
      n0 = *(const float4*)(ap);
      n1 = *(const float4*)(ap + 4);
      n2 = *(const float4*)(ap + 8);
      n3 = *(const float4*)(ap + 12);
#pragma unroll
      for (int i = 0; i < 8; ++i) {
        size_t so = (size_t)(br + 32 * i) * 4096 + (size_t)(kk + 1) * 64 + bj * 8;
        int db = (wid * 64 + 256 * i) * 16;
        gload16(Cth + so, (char*)&sBh[cur ^ 1][0] + db);
        gload16(Ctl + so, (char*)&sBl[cur ^ 1][0] + db);
      }
    }
    // raw barrier: A(kk) visible; B(kk) visible (drained by prev iter's
    // __syncthreads). Does NOT drain the in-flight B(kk+1) stage.
    asm volatile("s_waitcnt lgkmcnt(0)" ::: "memory");
    __builtin_amdgcn_s_barrier();
    asm volatile("" ::: "memory");

    const char* pA = (const char*)sA;
    const char* pBh = (const char*)&sBh[cur][0];
    const char* pBl = (const char*)&sBl[cur][0];
#pragma unroll
    for (int kc = 0; kc < 2; ++kc) {
      const int q = kc * 4 + lk;
      short8 af[2];
#pragma unroll
      for (int mi = 0; mi < 2; ++mi) {
        int rl = wm * 32 + mi * 16 + lr;
        af[mi] = *(const short8*)(pA + rl * 128 + ((q ^ (rl & 7)) << 4));
      }
#pragma unroll
      for (int ni = 0; ni < 8; ++ni) {
        int rb = wn * 128 + ni * 16 + lr;
        int so = rb * 128 + ((q ^ (rb & 7)) << 4);
        short8 bh = *(const short8*)(pBh + so);
        short8 bl = *(const short8*)(pBl + so);
#pragma unroll
        for (int mi = 0; mi < 2; ++mi) {
          acc[mi][ni] = __builtin_amdgcn_mfma_f32_16x16x32_bf16(af[mi], bh, acc[mi][ni], 0, 0, 0);
          acc[mi][ni] = __builtin_amdgcn_mfma_f32_16x16x32_bf16(af[mi], bl, acc[mi][ni], 0, 0, 0);
        }
      }
    }
    // drain next-tile stage (vmcnt(0)) + cross-wave reads-done fence
    __syncthreads();
    if (kk < 63) { a0 = n0; a1 = n1; a2 = n2; a3 = n3; }
  }

  // epilogue: add centering correction, X -> hi/lo bf16, pre-swizzled storage
  float cs[8];
#pragma unroll
  for (int ni = 0; ni < 8; ++ni) cs[ni] = csum[wn * 128 + ni * 16 + lr];
#pragma unroll
  for (int mi = 0; mi < 2; ++mi)
#pragma unroll
    for (int ni = 0; ni < 8; ++ni)
#pragma unroll
      for (int p = 0; p < 4; ++p) {
        int m = m0 + wm * 32 + mi * 16 + lk * 4 + p;  // C/D: row=(lane>>4)*4+reg
        int col = wn * 128 + ni * 16 + lr;            //      col=lane&15
        float x = acc[mi][ni][p] + cs[ni];
        unsigned short hi = f2bf(x);
        unsigned short lo = f2bf(x - bf2f(hi));
        size_t off = (size_t)m * 512 + ((col >> 6) << 7) +
                     ((((col >> 3) & 7) ^ (m & 7)) << 4) + ((col & 7) << 1);
        *(unsigned short*)((char*)Xhi + off) = hi;
        *(unsigned short*)((char*)Xlo + off) = lo;
      }
}

// ---------------------------------------------------------------------------
// stage 2: GI = Xhi@Whi + Xlo@Whi + Xhi@Wlo + fused GRU + level-mean.
// grid 256 (block = batch b), 256 thr, 4 waves 2Mx2N. X panel (hi+lo, 64 KB)
// resident in LDS; W tiles (96x256, 48 KB) staged once per (ntile, hi/lo).
// sC (epilogue) aliases the W buffer.
__global__ void __launch_bounds__(256) k_stage2(const unsigned short* __restrict__ Xhi,
                                                const unsigned short* __restrict__ Xlo,
                                                const unsigned short* __restrict__ Wph,
                                                const unsigned short* __restrict__ Wpl,
                                                const float* __restrict__ GH,
                                                const float* __restrict__ centers,
                                                const float* __restrict__ b_ih,
                                                float* __restrict__ out) {
  __shared__ __align__(16) char smem[114688];  // 112 KB
  short* sXh = (short*)smem;                   // [64][256] bf16 swz : 32 KB
  short* sXl = (short*)(smem + 32768);         // [64][256] bf16 swz : 32 KB
  char*  sW  = smem + 65536;                   // [96][256] bf16 swz : 48 KB
  float* sC  = (float*)(smem + 65536);         // [64][100] f32 (aliases sW)
  const int t = threadIdx.x;
  const int wid = t >> 6, l = t & 63;
  const int lr = l & 15, lk = l >> 4;
  const int wm = wid >> 1, wn = wid & 1;
  const int b = blockIdx.x;

  // stage X panel: rows b*64 .. b*64+63, straight 32 KB copies (pre-swizzled)
#pragma unroll
  for (int i = 0; i < 8; ++i) {
    int flat = t + 256 * i;
    size_t so = ((size_t)b * 64 + (flat >> 5)) * 512 + (size_t)(flat & 31) * 16;
    int db = (wid * 64 + 256 * i) * 16;
    gload16((const char*)Xhi + so, (char*)sXh + db);
    gload16((const char*)Xlo + so, (char*)sXl + db);
  }
  __syncthreads();

  for (int nt = 0; nt < 8; ++nt) {
    const int n0 = nt * 96;
    f32x4 acc[2][3];
#pragma unroll
    for (int i = 0; i < 2; ++i)
#pragma unroll
      for (int j = 0; j < 3; ++j) acc[i][j] = (f32x4){0.f, 0.f, 0.f, 0.f};

#pragma unroll
    for (int wp = 0; wp < 2; ++wp) {
      const unsigned short* Ws = wp ? Wpl : Wph;
      // stage W tile 96 x 512B
#pragma unroll
      for (int i = 0; i < 12; ++i) {
        int flat = t + 256 * i;
        size_t so = (size_t)(n0 + (flat >> 5)) * 512 + (size_t)(flat & 31) * 16;
        int db = (wid * 64 + 256 * i) * 16;
        gload16((const char*)Ws + so, sW + db);
      }
      __syncthreads();  // full drain: W visible
      const int np = wp ? 1 : 2;  // Wh: Xh,Xl passes; Wl: Xh pass
      for (int xp = 0; xp < np; ++xp) {
        const short* Xs = xp ? sXl : sXh;
#pragma unroll
        for (int kc = 0; kc < 8; ++kc) {
          const int q = kc * 4 + lk;
          const int seg = (q >> 3) << 7, jj = q & 7;
          short8 af[2];
#pragma unroll
          for (int mi = 0; mi < 2; ++mi) {
            int rl = wm * 32 + mi * 16 + lr;
            af[mi] = *(const short8*)((const char*)Xs + rl * 512 + seg + ((jj ^ (rl & 7)) << 4));
          }
#pragma unroll
          for (int ni = 0; ni < 3; ++ni) {
            int rw = wn * 48 + ni * 16 + lr;
            short8 bf = *(const short8*)(sW + rw * 512 + seg + ((jj ^ (rw & 7)) << 4));
#pragma unroll
            for (int mi = 0; mi < 2; ++mi)
              acc[mi][ni] = __builtin_amdgcn_mfma_f32_16x16x32_bf16(af[mi], bf, acc[mi][ni], 0, 0, 0);
          }
        }
      }
      __syncthreads();  // all sW reads done before restage / sC alias write
    }
    // acc -> sC (rows = slot s, cols = 3*hl + gate)
#pragma unroll
    for (int mi = 0; mi < 2; ++mi)
#pragma unroll
      for (int ni = 0; ni < 3; ++ni)
#pragma unroll
        for (int p = 0; p < 4; ++p) {
          int row = wm * 32 + mi * 16 + lk * 4 + p;
          int col = wn * 48 + ni * 16 + lr;
          sC[row * 100 + col] = acc[mi][ni][p];
        }
    __syncthreads();
    // fused GRU + level-mean: 16 o x 32 h = 512 items, 2 per thread
#pragma unroll
    for (int ii = 0; ii < 2; ++ii) {
      int item = t + 256 * ii;
      int hl = item & 31, o = item >> 5;
      int h = nt * 32 + hl;
      float hprev = centers[o * 256 + h];
      float bir = b_ih[h], biz = b_ih[256 + h], bin = b_ih[512 + h];
      float sum = 0.f;
#pragma unroll
      for (int j = 0; j < 4; ++j) {
        int s = 4 * o + j;
        float gir = sC[s * 100 + 3 * hl + 0] + bir;
        float giz = sC[s * 100 + 3 * hl + 1] + biz;
        float gin = sC[s * 100 + 3 * hl + 2] + bin;
        float rg = sigmf(gir + GH[s * 768 + h]);
        float zg = sigmf(giz + GH[s * 768 + 256 + h]);
        float ng = tanhf2(gin + rg * GH[s * 768 + 512 + h]);
        sum += (1.f - zg) * ng + zg * hprev;
      }
      out[(size_t)o * 65536 + (size_t)b * 256 + h] = 0.25f * sum;
    }
    __syncthreads();  // sC reads done before next ntile's sW stage (alias)
  }
}

// ---------------------------------------------------------------------------
extern "C" void kernel_launch(void* const* d_in, const int* in_sizes, int n_in,
                              void* d_out, int out_size, void* d_ws, size_t ws_size,
                              hipStream_t stream) {
  (void)in_sizes; (void)n_in; (void)out_size; (void)ws_size;
  const float* attn    = (const float*)d_in[0];  // [256][64][4096]
  const float* centers = (const float*)d_in[1];  // [4096][256]
  const float* w_ih    = (const float*)d_in[2];  // [768][256]
  const float* w_hh    = (const float*)d_in[3];  // [768][256]
  const float* b_ih    = (const float*)d_in[4];  // [768]
  const float* b_hh    = (const float*)d_in[5];  // [768]

  char* ws = (char*)d_ws;
  unsigned short* Cth = (unsigned short*)(ws + WS_CTH);
  unsigned short* Ctl = (unsigned short*)(ws + WS_CTL);
  unsigned short* Wph = (unsigned short*)(ws + WS_WPH);
  unsigned short* Wpl = (unsigned short*)(ws + WS_WPL);
  float*          GHp = (float*)(ws + WS_GH);
  float*          csp = (float*)(ws + WS_CSP);
  float*          cs  = (float*)(ws + WS_CS);
  unsigned short* Xhi = (unsigned short*)(ws + WS_XHI);
  unsigned short* Xlo = (unsigned short*)(ws + WS_XLO);
  float* out = (float*)d_out;

  hipLaunchKernelGGL(k_transC, dim3(64, 4), dim3(256), 0, stream, centers, Cth, Ctl);
  hipLaunchKernelGGL(k_csum, dim3(16), dim3(256), 0, stream, centers, csp);
  hipLaunchKernelGGL(k_csum2, dim3(1), dim3(256), 0, stream, csp, cs);
  hipLaunchKernelGGL(k_prepWp, dim3(96), dim3(256), 0, stream, w_ih, Wph, Wpl);
  hipLaunchKernelGGL(k_gh, dim3(64), dim3(256), 0, stream, centers, w_hh, b_hh, GHp);
  hipLaunchKernelGGL(k_stage1, dim3(256), dim3(256), 0, stream, attn, Cth, Ctl, cs, Xhi, Xlo);
  hipLaunchKernelGGL(k_stage2, dim3(256), dim3(256), 0, stream, Xhi, Xlo, Wph, Wpl, GHp, centers, b_ih, out);
}